// Round 1
// baseline (15.275 us; speedup 1.0000x reference)
//
#include <hip/hip_runtime.h>
#include <math.h>

#define N_NODES 2048
#define N_RELS 16
#define N_FEAT 256

// Kernel 1: A[r][n] = dot(x[n], relations[r]); B[n] = dot(x[n], outer_weight)
// One wave (64 lanes) per node; each lane holds a float4 slice of x[n].
__global__ void precompute_kernel(const float* __restrict__ x,
                                  const float* __restrict__ relations,
                                  const float* __restrict__ outer_weight,
                                  float* __restrict__ A,   // [N_RELS][N_NODES]
                                  float* __restrict__ B)   // [N_NODES]
{
    const int n = blockIdx.x;
    const int lane = threadIdx.x;  // 0..63

    const float4 xv = reinterpret_cast<const float4*>(x + n * N_FEAT)[lane];
    const float4 wv = reinterpret_cast<const float4*>(outer_weight)[lane];

    float b = xv.x * wv.x + xv.y * wv.y + xv.z * wv.z + xv.w * wv.w;
    #pragma unroll
    for (int off = 32; off > 0; off >>= 1) b += __shfl_xor(b, off, 64);
    if (lane == 0) B[n] = b;

    #pragma unroll
    for (int r = 0; r < N_RELS; ++r) {
        const float4 rv =
            reinterpret_cast<const float4*>(relations + r * N_FEAT)[lane];
        float a = xv.x * rv.x + xv.y * rv.y + xv.z * rv.z + xv.w * rv.w;
        #pragma unroll
        for (int off = 32; off > 0; off >>= 1) a += __shfl_xor(a, off, 64);
        if (lane == 0) A[r * N_NODES + n] = a;
    }
}

__device__ __forceinline__ float sigmoidf_fast(float z) {
    return 1.0f / (1.0f + __expf(-z));
}

// Kernel 2: out[e] = sigmoid(A[rel[e]][src[e]] * B[dst[e]])
// Vectorized: 4 edges per thread via int4 index loads.
__global__ void edge_kernel(const int* __restrict__ src,
                            const int* __restrict__ rel,
                            const int* __restrict__ dst,
                            const float* __restrict__ A,
                            const float* __restrict__ B,
                            float* __restrict__ out,
                            int E)
{
    const int t = blockIdx.x * blockDim.x + threadIdx.x;
    const int e4 = t * 4;
    if (e4 + 3 < E) {
        const int4 s = *reinterpret_cast<const int4*>(src + e4);
        const int4 r = *reinterpret_cast<const int4*>(rel + e4);
        const int4 d = *reinterpret_cast<const int4*>(dst + e4);
        float4 o;
        o.x = sigmoidf_fast(A[r.x * N_NODES + s.x] * B[d.x]);
        o.y = sigmoidf_fast(A[r.y * N_NODES + s.y] * B[d.y]);
        o.z = sigmoidf_fast(A[r.z * N_NODES + s.z] * B[d.z]);
        o.w = sigmoidf_fast(A[r.w * N_NODES + s.w] * B[d.w]);
        *reinterpret_cast<float4*>(out + e4) = o;
    } else {
        for (int e = e4; e < E; ++e) {
            out[e] = sigmoidf_fast(A[rel[e] * N_NODES + src[e]] * B[dst[e]]);
        }
    }
}

extern "C" void kernel_launch(void* const* d_in, const int* in_sizes, int n_in,
                              void* d_out, int out_size, void* d_ws, size_t ws_size,
                              hipStream_t stream) {
    const float* x            = (const float*)d_in[0];
    const float* relations    = (const float*)d_in[1];
    const float* outer_weight = (const float*)d_in[2];
    const int*   edge_index   = (const int*)d_in[3];

    const int E = in_sizes[3] / 3;  // edge_index is [3, E]: rows src, rel, dst
    const int* src = edge_index;
    const int* rel = edge_index + E;
    const int* dst = edge_index + 2 * E;

    float* A = (float*)d_ws;                       // 16*2048 floats = 128 KB
    float* B = A + N_RELS * N_NODES;               // 2048 floats = 8 KB

    precompute_kernel<<<N_NODES, 64, 0, stream>>>(x, relations, outer_weight, A, B);

    const int threads = 256;
    const int work = (E + 3) / 4;
    const int blocks = (work + threads - 1) / threads;
    edge_kernel<<<blocks, threads, 0, stream>>>(src, rel, dst, A, B,
                                                (float*)d_out, E);
}